// Round 10
// baseline (409.477 us; speedup 1.0000x reference)
//
#include <hip/hip_runtime.h>
#include <hip/hip_bf16.h>

// AdaGNN fused pipeline, round 10. Round 8/9 aborted because spmm_shard used
// UNCLAMPED gather indices: csr overreads hit 0xAA-poisoned workspace ->
// c = 0xAAAAAAAA (negative) -> (size_t)c*8 sign-extends -> page fault.
// Fix: clamp index before use (like gather_pair always did).
//   u~ = MLP(x)*dinv (row-major, aliases emb) ; v~ = dinv^2*S*u~ (SLICED) ;
//   w = dinv*S*v~ (SLICED, via XCD-feature-sharded gather: slice f=blockIdx&7
//   keeps a 3.2MB source region resident in that XCD's L2)
//   emb = relu( s*([u~|v~]@M_uv) + w@M_w + c0 ), s=sqrt(max(deg,1))
//   logits = emb @ W4.T + b4
// Sliced layout: X_S[(f*N + n)*8 + ff] = X[n][f*8+ff], f in [0,8).

#define IN_F 128
#define HF   64
#define MAXBINS 512
#define BIN_SHIFT 8          // 256 nodes per bin
#define BINCAP 5120          // slots per bin; mean 4096, sigma 64 -> 15+ sigma slack

typedef __attribute__((ext_vector_type(8))) short bf16x8;
typedef __attribute__((ext_vector_type(4))) float f32x4;

__device__ __forceinline__ unsigned short f2bf(float f) {
    unsigned u = __float_as_uint(f);
    return (unsigned short)((u + 0x7fffu + ((u >> 16) & 1u)) >> 16);
}
__device__ __forceinline__ float bf2f(unsigned short h) {
    return __uint_as_float(((unsigned)h) << 16);
}
__device__ __forceinline__ void split8(const float* x8, bf16x8& hi, bf16x8& lo) {
    #pragma unroll
    for (int e = 0; e < 8; ++e) {
        float v = x8[e];
        unsigned short h = f2bf(v);
        float r = v - bf2f(h);
        hi[e] = (short)h;
        lo[e] = (short)f2bf(r);
    }
}

// ---------------- phase A: bin edges by dst>>8 via LDS histogram ----------------
__global__ __launch_bounds__(256) void binA(int E_, const int* __restrict__ src,
        const int* __restrict__ dst, unsigned* __restrict__ binPos,
        unsigned* __restrict__ binned) {
    __shared__ unsigned hist[MAXBINS];
    __shared__ unsigned base[MAXBINS];
    int t = threadIdx.x;
    for (int i = t; i < MAXBINS; i += 256) hist[i] = 0u;
    __syncthreads();
    int e0 = blockIdx.x * 4096;
    unsigned pk[16], key[16];
    #pragma unroll
    for (int i = 0; i < 16; ++i) {
        int e = e0 + i * 256 + t;
        if (e < E_) {
            int d = dst[e], s = src[e];
            unsigned b = (unsigned)d >> BIN_SHIFT;
            unsigned slot = atomicAdd(&hist[b], 1u);      // LDS atomic, returns local slot
            pk[i]  = ((unsigned)(d & 255) << 24) | (unsigned)s;
            key[i] = (slot << 9) | b;                     // slot<4096, b<512
        } else key[i] = 0xFFFFFFFFu;
    }
    __syncthreads();
    for (int i = t; i < MAXBINS; i += 256) {
        unsigned h = hist[i];
        base[i] = h ? atomicAdd(&binPos[i], h) : 0u;      // one global atomic per (block,bin)
    }
    __syncthreads();
    #pragma unroll
    for (int i = 0; i < 16; ++i) {
        if (key[i] != 0xFFFFFFFFu) {
            unsigned b = key[i] & 511u;
            unsigned pos = base[b] + (key[i] >> 9);
            if (pos < BINCAP) binned[(size_t)b * BINCAP + pos] = pk[i];
        }
    }
}

// ---------------- phase B: per-bin local CSR + deg + dinv ----------------
__global__ __launch_bounds__(256) void binB(int N_,
        const unsigned* __restrict__ binPos, const unsigned* __restrict__ binned,
        unsigned* __restrict__ deg, float* __restrict__ dinv,
        int* __restrict__ row_start, int* __restrict__ csr) {
    __shared__ unsigned cnt[256];
    __shared__ unsigned scn[256];
    int b = blockIdx.x, t = threadIdx.x;
    int nb = min((int)binPos[b], BINCAP);
    size_t base = (size_t)b * BINCAP;
    cnt[t] = 0u;
    __syncthreads();
    for (int i = t; i < nb; i += 256)
        atomicAdd(&cnt[binned[base + i] >> 24], 1u);
    __syncthreads();
    unsigned my = cnt[t];
    scn[t] = my;
    __syncthreads();
    #pragma unroll
    for (int off = 1; off < 256; off <<= 1) {
        unsigned v = (t >= off) ? scn[t - off] : 0u;
        __syncthreads();
        scn[t] += v;
        __syncthreads();
    }
    unsigned ex = scn[t] - my;                             // exclusive scan
    int node = b * 256 + t;
    if (node < N_) {
        deg[node] = my;
        dinv[node] = 1.0f / sqrtf(fmaxf((float)my, 1.0f));
        row_start[node] = (int)(base + ex);
    }
    cnt[t] = ex;                                           // running slot counters
    __syncthreads();
    for (int i = t; i < nb; i += 256) {
        unsigned p = binned[base + i];
        unsigned slot = atomicAdd(&cnt[p >> 24], 1u);      // LDS
        csr[base + slot] = (int)(p & 0xFFFFFFu);
    }
}

// ---------------- prep (17 blocks): blocks 0..15 build M; block 16 splits + c0 ----------------
__global__ __launch_bounds__(256) void prep_kernel(
        const float* __restrict__ W1, const float* __restrict__ W2,
        const float* __restrict__ W3, const float* __restrict__ b3,
        const float* __restrict__ cW1,
        const float* __restrict__ ld1, const float* __restrict__ cb1,
        const float* __restrict__ ld2, const float* __restrict__ cb2,
        const float* __restrict__ ld3, const float* __restrict__ cb3,
        unsigned short* __restrict__ W1h, unsigned short* __restrict__ W1l,
        unsigned short* __restrict__ W2h, unsigned short* __restrict__ W2l,
        unsigned short* __restrict__ Mh,  unsigned short* __restrict__ Ml,
        float* __restrict__ c0v) {
    int tid = threadIdx.x, bid = blockIdx.x;
    if (bid < 16) {
        // THETAS=((3,-3,.75),(0,3,-1.5),(0,0,.75)):
        // coeff on u: t1+t2 ; on v: -(t1*a + t2*(a+b)) ; on w: t2*a*b  (a=ld[1],b=ld[2])
        int t = bid * 256 + tid;              // t in [0, 4096)
        int k = t >> 6, j = t & 63;
        float w3a = W3[j * 192 + k], w3b = W3[j * 192 + 64 + k], w3c = W3[j * 192 + 128 + k];
        float a1 = ld1[64 + k], bb1 = ld1[128 + k];
        float a2 = ld2[64 + k], bb2 = ld2[128 + k];
        float a3 = ld3[64 + k], bb3 = ld3[128 + k];
        float g = 0.f;   // branch1 cW1 folded through W3 block 1
        for (int i = 0; i < 64; ++i) g += cW1[i * 64 + k] * W3[j * 192 + i];
        float m0 = -2.25f * w3a + 1.5f * w3b + 0.75f * w3c + 3.0f * ld1[k] * g;
        float m1 = (2.25f * a1 - 0.75f * bb1) * w3a
                 + (1.5f * (bb2 - a2)) * w3b
                 + (-0.75f * (a3 + bb3)) * w3c;
        float m2 = (0.75f * a1 * bb1) * w3a
                 + (-1.5f * a2 * bb2) * w3b
                 + (0.75f * a3 * bb3) * w3c;
        unsigned short h;
        h = f2bf(m0); Mh[j * 192 + k]       = h; Ml[j * 192 + k]       = f2bf(m0 - bf2f(h));
        h = f2bf(m1); Mh[j * 192 + 64 + k]  = h; Ml[j * 192 + 64 + k]  = f2bf(m1 - bf2f(h));
        h = f2bf(m2); Mh[j * 192 + 128 + k] = h; Ml[j * 192 + 128 + k] = f2bf(m2 - bf2f(h));
    } else {
        for (int i = tid; i < 64 * 128; i += 256) {
            float v = W1[i]; unsigned short h = f2bf(v);
            W1h[i] = h; W1l[i] = f2bf(v - bf2f(h));
        }
        for (int i = tid; i < 64 * 64; i += 256) {
            float v = W2[i]; unsigned short h = f2bf(v);
            W2h[i] = h; W2l[i] = f2bf(v - bf2f(h));
        }
        if (tid < 64) {
            float s = b3[tid];
            for (int k = 0; k < 64; ++k)
                s += cb1[k] * W3[tid * 192 + k] + cb2[k] * W3[tid * 192 + 64 + k]
                   + cb3[k] * W3[tid * 192 + 128 + k];
            c0v[tid] = s;
        }
    }
}

// ---------------- MLP via MFMA: u~ = relu(relu(X@W1.T+b1)@W2.T+b2) * dinv ----------------
__global__ __launch_bounds__(256) void mlp_mfma(int N_,
        const float* __restrict__ X,
        const unsigned short* __restrict__ W1h, const unsigned short* __restrict__ W1l,
        const unsigned short* __restrict__ W2h, const unsigned short* __restrict__ W2l,
        const float* __restrict__ b1, const float* __restrict__ b2,
        const float* __restrict__ dinv,
        float* __restrict__ ut) {
    __shared__ float hst[4][16][68];   // per-wave h staging, row pad 68
    int tid = threadIdx.x, w = tid >> 6, l = tid & 63;
    int lr = l & 15, kb = l >> 4;
    int g0 = blockIdx.x * 64 + w * 16;

    f32x4 acc[4];
    #pragma unroll
    for (int nt = 0; nt < 4; ++nt) { float b = b1[nt * 16 + lr]; acc[nt] = (f32x4){b, b, b, b}; }

    int arow = min(g0 + lr, N_ - 1);
    const float* xr = X + (size_t)arow * IN_F;
    #pragma unroll
    for (int ks = 0; ks < 4; ++ks) {
        float x8[8];
        *(float4*)&x8[0] = *(const float4*)(xr + ks * 32 + kb * 8);
        *(float4*)&x8[4] = *(const float4*)(xr + ks * 32 + kb * 8 + 4);
        bf16x8 ah, al; split8(x8, ah, al);
        #pragma unroll
        for (int nt = 0; nt < 4; ++nt) {
            int j = nt * 16 + lr;
            bf16x8 bh = *(const bf16x8*)(W1h + j * 128 + ks * 32 + kb * 8);
            bf16x8 bl = *(const bf16x8*)(W1l + j * 128 + ks * 32 + kb * 8);
            acc[nt] = __builtin_amdgcn_mfma_f32_16x16x32_bf16(al, bh, acc[nt], 0, 0, 0);
            acc[nt] = __builtin_amdgcn_mfma_f32_16x16x32_bf16(ah, bl, acc[nt], 0, 0, 0);
            acc[nt] = __builtin_amdgcn_mfma_f32_16x16x32_bf16(ah, bh, acc[nt], 0, 0, 0);
        }
    }
    #pragma unroll
    for (int nt = 0; nt < 4; ++nt)
        #pragma unroll
        for (int r = 0; r < 4; ++r)
            hst[w][kb * 4 + r][nt * 16 + lr] = fmaxf(acc[nt][r], 0.f);
    __syncthreads();

    #pragma unroll
    for (int nt = 0; nt < 4; ++nt) { float b = b2[nt * 16 + lr]; acc[nt] = (f32x4){b, b, b, b}; }
    #pragma unroll
    for (int ks = 0; ks < 2; ++ks) {
        float x8[8];
        *(float4*)&x8[0] = *(const float4*)&hst[w][lr][ks * 32 + kb * 8];
        *(float4*)&x8[4] = *(const float4*)&hst[w][lr][ks * 32 + kb * 8 + 4];
        bf16x8 ah, al; split8(x8, ah, al);
        #pragma unroll
        for (int nt = 0; nt < 4; ++nt) {
            int j = nt * 16 + lr;
            bf16x8 bh = *(const bf16x8*)(W2h + j * 64 + ks * 32 + kb * 8);
            bf16x8 bl = *(const bf16x8*)(W2l + j * 64 + ks * 32 + kb * 8);
            acc[nt] = __builtin_amdgcn_mfma_f32_16x16x32_bf16(al, bh, acc[nt], 0, 0, 0);
            acc[nt] = __builtin_amdgcn_mfma_f32_16x16x32_bf16(ah, bl, acc[nt], 0, 0, 0);
            acc[nt] = __builtin_amdgcn_mfma_f32_16x16x32_bf16(ah, bh, acc[nt], 0, 0, 0);
        }
    }
    #pragma unroll
    for (int r = 0; r < 4; ++r) {
        int node = g0 + kb * 4 + r;
        if (node < N_) {
            float dn = dinv[node];
            #pragma unroll
            for (int nt = 0; nt < 4; ++nt)
                ut[(size_t)node * HF + nt * 16 + lr] = fmaxf(acc[nt][r], 0.f) * dn;
        }
    }
}

// ---------------- pair gather (row-major source; indices clamped pre-use) ----------------
__device__ __forceinline__ void gather_pair(const float* __restrict__ in,
        const unsigned* __restrict__ deg, const int* __restrict__ row_start,
        const int* __restrict__ csr, int n0, int n1, bool has1, int lane,
        float& accA, float& accB) {
    int sA = row_start[n0], sB = row_start[n1];
    int eA = (int)deg[n0];
    int eB = has1 ? (int)deg[n1] : 0;
    accA = 0.f; accB = 0.f;
    int em = max(eA, eB);
    for (int i = 0; i < em; i += 8) {
        int ca[8], cb[8];
        float va[8], vb[8];
        #pragma unroll
        for (int j = 0; j < 8; ++j) {
            ca[j] = csr[sA + i + j];
            cb[j] = csr[sB + i + j];
        }
        #pragma unroll
        for (int j = 0; j < 8; ++j) {
            int iA = (i + j < eA) ? ca[j] : n0;   // clamp BEFORE use as index
            int iB = (i + j < eB) ? cb[j] : n0;
            va[j] = in[(size_t)iA * HF + lane];
            vb[j] = in[(size_t)iB * HF + lane];
        }
        #pragma unroll
        for (int j = 0; j < 8; ++j) {
            accA += (i + j < eA) ? va[j] : 0.f;
            accB += (i + j < eB) ? vb[j] : 0.f;
        }
    }
}

// ---------------- SpMM1 (v~): gathers row-major u~, writes SLICED v~ ----------------
__global__ __launch_bounds__(256) void spmm_gather(int N_,
        const float* __restrict__ in, const float* __restrict__ dinv,
        const unsigned* __restrict__ deg, const int* __restrict__ row_start,
        const int* __restrict__ csr, float* __restrict__ outS) {
    int gw = (blockIdx.x * blockDim.x + threadIdx.x) >> 6;
    int lane = threadIdx.x & 63;
    int f = lane >> 3, ff = lane & 7;
    int nw = (gridDim.x * blockDim.x) >> 6;
    for (int n0 = gw * 2; n0 < N_; n0 += nw * 2) {
        bool has1 = (n0 + 1) < N_;
        int n1 = has1 ? n0 + 1 : n0;
        float accA, accB;
        gather_pair(in, deg, row_start, csr, n0, n1, has1, lane, accA, accB);
        float dnA = dinv[n0];
        outS[((size_t)f * N_ + n0) * 8 + ff] = accA * dnA * dnA;
        if (has1) {
            float dnB = dinv[n1];
            outS[((size_t)f * N_ + n1) * 8 + ff] = accB * dnB * dnB;
        }
    }
}

// ---------------- SpMM2 (w): XCD-sharded gather of SLICED v~ -> SLICED w ----------------
// block b: slice f = b&7 (round-robin blockIdx->XCD keeps the 3.2MB slice
// region L2-resident), node chunk = b>>3 (32 nodes/block; 8 nodes/wave,
// 8 feature-lanes per node). Indices CLAMPED before use (poisoned-slack fix).
__global__ __launch_bounds__(256) void spmm_shard(int N_,
        const float* __restrict__ vtS, const float* __restrict__ dinv,
        const unsigned* __restrict__ deg, const int* __restrict__ row_start,
        const int* __restrict__ csr, float* __restrict__ wS) {
    int b = blockIdx.x;
    int f = b & 7;
    int chunk = b >> 3;
    int t = threadIdx.x, wv = t >> 6, l = t & 63;
    int g = l >> 3, ff = l & 7;
    int n = chunk * 32 + wv * 8 + g;
    const float* __restrict__ src = vtS + (size_t)f * N_ * 8;
    int dg = 0, rs = 0;
    if (n < N_) { dg = (int)deg[n]; rs = row_start[n]; }
    int dmax = dg;
    dmax = max(dmax, __shfl_xor(dmax, 8, 64));
    dmax = max(dmax, __shfl_xor(dmax, 16, 64));
    dmax = max(dmax, __shfl_xor(dmax, 32, 64));
    float acc = 0.f;
    for (int i = 0; i < dmax; i += 4) {
        int c0 = csr[rs + i];
        int c1 = csr[rs + i + 1];
        int c2 = csr[rs + i + 2];
        int c3 = csr[rs + i + 3];
        c0 = (i     < dg) ? c0 : 0;   // clamp BEFORE use as index
        c1 = (i + 1 < dg) ? c1 : 0;
        c2 = (i + 2 < dg) ? c2 : 0;
        c3 = (i + 3 < dg) ? c3 : 0;
        float v0 = src[(size_t)c0 * 8 + ff];
        float v1 = src[(size_t)c1 * 8 + ff];
        float v2 = src[(size_t)c2 * 8 + ff];
        float v3 = src[(size_t)c3 * 8 + ff];
        acc += (i     < dg) ? v0 : 0.f;
        acc += (i + 1 < dg) ? v1 : 0.f;
        acc += (i + 2 < dg) ? v2 : 0.f;
        acc += (i + 3 < dg) ? v3 : 0.f;
    }
    if (n < N_) wS[((size_t)f * N_ + n) * 8 + ff] = acc * dinv[n];
}

// ---------------- final via MFMA: pure streaming ----------------
// emb = relu( s*([u~|v~]@M_uv^T) + w@M_w^T + c0 ), s = sqrt(max(deg,1));
// logits = emb @ W4.T + b4.  u~ (row-major) aliases the emb output region:
// each block reads only its own rows before its epilogue writes them.
__global__ __launch_bounds__(256) void final_mfma(int N_,
        const float* __restrict__ ut, const float* __restrict__ vtS,
        const float* __restrict__ wS, const unsigned* __restrict__ deg,
        const unsigned short* __restrict__ Mh, const unsigned short* __restrict__ Ml,
        const float* __restrict__ c0v, const float* __restrict__ W4, const float* __restrict__ b4,
        float* __restrict__ logits, float* __restrict__ emb) {
    int tid = threadIdx.x, w = tid >> 6, l = tid & 63;
    int lr = l & 15, kb = l >> 4;
    int g0 = blockIdx.x * 64 + w * 16;

    f32x4 accS[4], accW[4];
    #pragma unroll
    for (int nt = 0; nt < 4; ++nt) {
        accS[nt] = (f32x4){0.f, 0.f, 0.f, 0.f};
        float b = c0v[nt * 16 + lr];
        accW[nt] = (f32x4){b, b, b, b};
    }
    int arow = min(g0 + lr, N_ - 1);
    #pragma unroll
    for (int ks = 0; ks < 6; ++ks) {
        const float* xr;
        if (ks < 2)      xr = ut  + (size_t)arow * HF + ks * 32 + kb * 8;
        else if (ks < 4) xr = vtS + ((size_t)((ks - 2) * 4 + kb) * N_ + arow) * 8;
        else             xr = wS  + ((size_t)((ks - 4) * 4 + kb) * N_ + arow) * 8;
        float x8[8];
        *(float4*)&x8[0] = *(const float4*)(xr);
        *(float4*)&x8[4] = *(const float4*)(xr + 4);
        bf16x8 ah, al; split8(x8, ah, al);
        #pragma unroll
        for (int nt = 0; nt < 4; ++nt) {
            int j = nt * 16 + lr;
            bf16x8 bh = *(const bf16x8*)(Mh + j * 192 + ks * 32 + kb * 8);
            bf16x8 bl = *(const bf16x8*)(Ml + j * 192 + ks * 32 + kb * 8);
            if (ks < 4) {
                accS[nt] = __builtin_amdgcn_mfma_f32_16x16x32_bf16(al, bh, accS[nt], 0, 0, 0);
                accS[nt] = __builtin_amdgcn_mfma_f32_16x16x32_bf16(ah, bl, accS[nt], 0, 0, 0);
                accS[nt] = __builtin_amdgcn_mfma_f32_16x16x32_bf16(ah, bh, accS[nt], 0, 0, 0);
            } else {
                accW[nt] = __builtin_amdgcn_mfma_f32_16x16x32_bf16(al, bh, accW[nt], 0, 0, 0);
                accW[nt] = __builtin_amdgcn_mfma_f32_16x16x32_bf16(ah, bl, accW[nt], 0, 0, 0);
                accW[nt] = __builtin_amdgcn_mfma_f32_16x16x32_bf16(ah, bh, accW[nt], 0, 0, 0);
            }
        }
    }
    float w4c0[4], w4c1[4];
    #pragma unroll
    for (int nt = 0; nt < 4; ++nt) { w4c0[nt] = W4[nt * 16 + lr]; w4c1[nt] = W4[64 + nt * 16 + lr]; }
    float b40 = b4[0], b41 = b4[1];
    #pragma unroll
    for (int r = 0; r < 4; ++r) {
        int node = g0 + kb * 4 + r;
        int cn = min(node, N_ - 1);
        float s = sqrtf(fmaxf((float)deg[cn], 1.0f));
        float p0 = 0.f, p1 = 0.f;
        float ev[4];
        #pragma unroll
        for (int nt = 0; nt < 4; ++nt) {
            ev[nt] = fmaxf(accS[nt][r] * s + accW[nt][r], 0.f);
            p0 += ev[nt] * w4c0[nt];
            p1 += ev[nt] * w4c1[nt];
        }
        #pragma unroll
        for (int m = 1; m < 16; m <<= 1) {
            p0 += __shfl_xor(p0, m, 64);
            p1 += __shfl_xor(p1, m, 64);
        }
        if (node < N_) {
            #pragma unroll
            for (int nt = 0; nt < 4; ++nt)
                emb[(size_t)node * HF + nt * 16 + lr] = ev[nt];
            if (lr == 0) {
                logits[(size_t)node * 2]     = p0 + b40;
                logits[(size_t)node * 2 + 1] = p1 + b41;
            }
        }
    }
}

extern "C" void kernel_launch(void* const* d_in, const int* in_sizes, int n_in,
                              void* d_out, int out_size, void* d_ws, size_t ws_size,
                              hipStream_t stream) {
    const float* in_feat = (const float*)d_in[0];
    const int*   src     = (const int*)d_in[1];
    const int*   dst     = (const int*)d_in[2];
    const float* W1 = (const float*)d_in[3];
    const float* b1 = (const float*)d_in[4];
    const float* W2 = (const float*)d_in[5];
    const float* b2 = (const float*)d_in[6];
    const float* W3 = (const float*)d_in[7];
    const float* b3 = (const float*)d_in[8];
    const float* W4 = (const float*)d_in[9];
    const float* b4 = (const float*)d_in[10];
    const float* ld1 = (const float*)d_in[11];
    const float* cW1 = (const float*)d_in[12];
    const float* cb1 = (const float*)d_in[13];
    const float* ld2 = (const float*)d_in[14];
    const float* cb2 = (const float*)d_in[16];
    const float* ld3 = (const float*)d_in[17];
    const float* cb3 = (const float*)d_in[19];

    int N_ = in_sizes[0] / IN_F;
    int E_ = in_sizes[1];
    int nbins = (N_ + 255) >> BIN_SHIFT;

    char* p = (char*)d_ws;
    auto alloc = [&](size_t bytes) -> char* {
        char* r = p;
        p += (bytes + 511) & ~(size_t)511;
        return r;
    };
    unsigned* binPos    = (unsigned*)alloc((size_t)MAXBINS * 4);           // zeroed below
    unsigned* deg       = (unsigned*)alloc((size_t)N_ * 4);
    float*    dinv      = (float*)alloc((size_t)N_ * 4);
    int*      row_start = (int*)alloc((size_t)N_ * 4);
    unsigned* binned    = (unsigned*)alloc((size_t)nbins * BINCAP * 4);
    int*      csr       = (int*)alloc((size_t)nbins * BINCAP * 4 + 4096);  // +slack for overreads
    float*    vtS       = (float*)alloc((size_t)N_ * HF * 4);              // v~ sliced [8][N][8]
    float*    wS        = (float*)alloc((size_t)N_ * HF * 4);              // w  sliced [8][N][8]
    unsigned short* W1h = (unsigned short*)alloc(64 * 128 * 2);
    unsigned short* W1l = (unsigned short*)alloc(64 * 128 * 2);
    unsigned short* W2h = (unsigned short*)alloc(64 * 64 * 2);
    unsigned short* W2l = (unsigned short*)alloc(64 * 64 * 2);
    unsigned short* Mh  = (unsigned short*)alloc(64 * 192 * 2);
    unsigned short* Ml  = (unsigned short*)alloc(64 * 192 * 2);
    float* c0v = (float*)alloc(64 * 4);

    float* logits = (float*)d_out;                   // N x 2
    float* emb    = (float*)d_out + (size_t)N_ * 2;  // N x 64
    float* ut     = emb;                             // u~ (row-major) aliases emb region

    hipMemsetAsync(binPos, 0, (size_t)MAXBINS * 4, stream);

    int ab = (E_ + 4095) / 4096;
    int gb = (N_ + 63) / 64;
    int sb = 8 * ((N_ + 31) / 32);   // sharded spmm2 grid

    binA<<<ab, 256, 0, stream>>>(E_, src, dst, binPos, binned);
    binB<<<nbins, 256, 0, stream>>>(N_, binPos, binned, deg, dinv, row_start, csr);
    prep_kernel<<<17, 256, 0, stream>>>(W1, W2, W3, b3, cW1, ld1, cb1, ld2, cb2, ld3, cb3,
                                        W1h, W1l, W2h, W2l, Mh, Ml, c0v);
    mlp_mfma<<<gb, 256, 0, stream>>>(N_, in_feat, W1h, W1l, W2h, W2l, b1, b2, dinv, ut);
    spmm_gather<<<2048, 256, 0, stream>>>(N_, ut, dinv, deg, row_start, csr, vtS);  // v~ (sliced out)
    spmm_shard<<<sb, 256, 0, stream>>>(N_, vtS, dinv, deg, row_start, csr, wS);     // w  (sharded)
    final_mfma<<<gb, 256, 0, stream>>>(N_, ut, vtS, wS, deg, Mh, Ml, c0v, W4, b4, logits, emb);
}